// Round 1
// baseline (437.807 us; speedup 1.0000x reference)
//
#include <hip/hip_runtime.h>

// HebbFF: T=128, B=8, N=512, D=256, O=1. Persistent-kernel design:
// 8 groups (one per batch) x 16 blocks x 512 threads. State in registers:
// each wave owns 4 rows of A_mult (4 f32/lane) and A_add (8 f32/lane, fused
// with w_add). One spin barrier per group per timestep, fully overlapped
// with compute. Workspace layout (floats):
//   [0..1023]          barrier ints (cnt at g*64, gen at g*64+32)
//   [1024..17407]      h_mult quad buffer: 4 * B * N
//   [17408..33791]     y partials: [g][blk][t]  (line-exclusive per block)
// requires ws_size >= 135168 bytes.

#define T_ 128
#define B_ 8
#define N_ 512
#define D_ 256
#define GB 16            // blocks per group
#define NTHREADS 512
#define NWAVES 8
#define RW 4             // rows per wave = N_ / (GB*NWAVES)

#define SCOPE __HIP_MEMORY_SCOPE_AGENT

__device__ __forceinline__ float g_loadf(const float* p) {
  return __hip_atomic_load(p, __ATOMIC_RELAXED, SCOPE);
}
__device__ __forceinline__ void g_storef(float* p, float v) {
  __hip_atomic_store(p, v, __ATOMIC_RELAXED, SCOPE);
}
__device__ __forceinline__ float wave_sum(float v) {
#pragma unroll
  for (int m = 1; m < 64; m <<= 1) v += __shfl_xor(v, m, 64);
  return v;
}
__device__ __forceinline__ float sigmoid_f(float z) {
  return __builtin_amdgcn_rcpf(1.f + __expf(-z));
}
__device__ __forceinline__ float tanh_f(float z) {
  // tanh(z) = 1 - 2/(1+e^{2z}); saturates correctly for |z| large
  return 1.f - 2.f * __builtin_amdgcn_rcpf(1.f + __expf(2.f * z));
}

__global__ void __launch_bounds__(NTHREADS, 2)
hebb_main(const float* __restrict__ x, const float* __restrict__ w_mult,
          const float* __restrict__ b_mult, const float* __restrict__ w_add,
          const float* __restrict__ b_add, const float* __restrict__ w_final,
          const float* __restrict__ p_lm, const float* __restrict__ p_la,
          const float* __restrict__ p_em, const float* __restrict__ p_ea,
          float* __restrict__ ws) {
  const int g    = blockIdx.x & 7;    // batch / group (XCD-affine if rr mapping)
  const int blk  = blockIdx.x >> 3;   // 0..15 within group
  const int tid  = threadIdx.x;
  const int wave = tid >> 6;
  const int lane = tid & 63;
  const int n0   = (blk * NWAVES + wave) * RW;

  int*   cnt  = (int*)ws + g * 64;
  int*   gen  = (int*)ws + g * 64 + 32;
  float* hbuf = ws + 1024;                  // 4 * B_ * N_
  float* part = hbuf + 4 * B_ * N_;         // [g][blk][t]

  __shared__ float hp[N_];
  __shared__ float pp[NWAVES];

  const float lam_m = sigmoid_f(p_lm[0]);
  const float lam_a = sigmoid_f(p_la[0]);
  const float eta_m = p_em[0];
  const float eta_a = p_ea[0];

  // Register-resident state + weights.
  float wm[RW][4], Am[RW][4], Sa[RW][8], wb[RW][8];
  float bm[RW], ba[RW], wf[RW];
#pragma unroll
  for (int r = 0; r < RW; ++r) {
    const int n = n0 + r;
    bm[r] = b_mult[n];
    ba[r] = b_add[n];
    wf[r] = w_final[n];
#pragma unroll
    for (int j = 0; j < 4; ++j) {
      wm[r][j] = w_mult[n * D_ + lane + 64 * j];
      Am[r][j] = 0.f;
    }
#pragma unroll
    for (int k = 0; k < 8; ++k) {
      const float wa = w_add[n * N_ + lane + 64 * k];
      Sa[r][k] = wa;                      // S = A_add + w_add, A_add(0)=0
      wb[r][k] = (1.f - lam_a) * wa;      // update constant term
    }
  }

  // part1(t): h_mult(t) = tanh(sum_d wm*(Am+1)*x + bm); update Am; publish.
  auto part1 = [&](int t) {
    const float* xt = x + (t * B_ + g) * D_;
    float xv[4];
#pragma unroll
    for (int j = 0; j < 4; ++j) xv[j] = xt[lane + 64 * j];
    float* hb = hbuf + (t & 3) * (B_ * N_) + g * N_;
    float hmv[RW];
#pragma unroll
    for (int r = 0; r < RW; ++r) {
      float acc = 0.f;
#pragma unroll
      for (int j = 0; j < 4; ++j) {
        const float wx = wm[r][j] * xv[j];
        acc = __builtin_fmaf(wx, Am[r][j], acc) + wx;
      }
      acc = wave_sum(acc) + bm[r];
      const float hm = tanh_f(acc);
      hmv[r] = hm;
      const float c = eta_m * hm;
#pragma unroll
      for (int j = 0; j < 4; ++j)
        Am[r][j] = __builtin_fmaf(lam_m, Am[r][j], c * xv[j]);
    }
    if (lane == 0) {
#pragma unroll
      for (int r = 0; r < RW; ++r) g_storef(hb + n0 + r, hmv[r]);
    }
  };

  // Prologue: publish h_mult(0), arrive(0), precompute h_mult(1).
  part1(0);
  __syncthreads();  // drains all waves' publish stores (vmcnt 0)
  if (tid == 0) {
    if (__hip_atomic_fetch_add(cnt, 1, __ATOMIC_RELAXED, SCOPE) == GB - 1)
      __hip_atomic_store(gen, 1, __ATOMIC_RELAXED, SCOPE);
  }
  part1(1);

  for (int t = 1; t <= T_; ++t) {
    // wait(t-1)
    if (tid == 0) {
      while (__hip_atomic_load(gen, __ATOMIC_ACQUIRE, SCOPE) < t) {}
    }
    __syncthreads();  // releases block; drains part1(t) stores before arrive(t)
    // arrive(t) immediately -> whole compute body overlaps the barrier
    if (t < T_ && tid == 0) {
      if (__hip_atomic_fetch_add(cnt, 1, __ATOMIC_RELAXED, SCOPE) ==
          (t + 1) * GB - 1)
        __hip_atomic_store(gen, t + 1, __ATOMIC_RELAXED, SCOPE);
    }
    // part2(t-1): h_add, A_add update, y partial
    {
      const float* hb = hbuf + ((t - 1) & 3) * (B_ * N_) + g * N_;
      hp[tid] = g_loadf(hb + tid);
      __syncthreads();
      float hpv[8];
#pragma unroll
      for (int k = 0; k < 8; ++k) hpv[k] = hp[lane + 64 * k];
      float py = 0.f;
#pragma unroll
      for (int r = 0; r < RW; ++r) {
        float acc = 0.f;
#pragma unroll
        for (int k = 0; k < 8; ++k)
          acc = __builtin_fmaf(Sa[r][k], hpv[k], acc);
        acc = wave_sum(acc) + ba[r];
        const float ha = sigmoid_f(acc);
        const float c = eta_a * ha;
#pragma unroll
        for (int k = 0; k < 8; ++k)
          Sa[r][k] = __builtin_fmaf(lam_a, Sa[r][k],
                                    __builtin_fmaf(c, hpv[k], wb[r][k]));
        py = __builtin_fmaf(wf[r], ha, py);
      }
      if (lane == 0) pp[wave] = py;
      __syncthreads();
      if (tid == 0) {
        float s = 0.f;
#pragma unroll
        for (int w = 0; w < NWAVES; ++w) s += pp[w];
        part[(g * GB + blk) * T_ + (t - 1)] = s;  // plain store, read next kernel
      }
    }
    // part1(t+1): independent of barrier t -> also overlaps it
    if (t + 1 < T_) part1(t + 1);
  }
}

__global__ void hebb_final(const float* __restrict__ ws,
                           const float* __restrict__ b_final,
                           float* __restrict__ out) {
  const int tb = blockIdx.x * blockDim.x + threadIdx.x;  // t*8 + b
  if (tb >= T_ * B_) return;
  const int t = tb >> 3, b = tb & 7;
  const float* part = ws + 1024 + 4 * B_ * N_;
  float s = b_final[0];
#pragma unroll
  for (int blk = 0; blk < GB; ++blk) s += part[(b * GB + blk) * T_ + t];
  out[tb] = sigmoid_f(s);
}

extern "C" void kernel_launch(void* const* d_in, const int* in_sizes, int n_in,
                              void* d_out, int out_size, void* d_ws,
                              size_t ws_size, hipStream_t stream) {
  const float* x       = (const float*)d_in[0];
  const float* w_mult  = (const float*)d_in[1];
  const float* b_mult  = (const float*)d_in[2];
  const float* w_add   = (const float*)d_in[3];
  const float* b_add   = (const float*)d_in[4];
  const float* w_final = (const float*)d_in[5];
  const float* b_final = (const float*)d_in[6];
  const float* p_lm    = (const float*)d_in[7];
  const float* p_la    = (const float*)d_in[8];
  const float* p_em    = (const float*)d_in[9];
  const float* p_ea    = (const float*)d_in[10];
  float* out = (float*)d_out;
  float* ws  = (float*)d_ws;

  // Barrier counters/generations must start at 0 every call (ws is poisoned
  // once and never re-poisoned between graph replays).
  hipMemsetAsync(d_ws, 0, 4096, stream);
  hipLaunchKernelGGL(hebb_main, dim3(GB * B_), dim3(NTHREADS), 0, stream,
                     x, w_mult, b_mult, w_add, b_add, w_final,
                     p_lm, p_la, p_em, p_ea, ws);
  hipLaunchKernelGGL(hebb_final, dim3(2), dim3(512), 0, stream,
                     ws, b_final, out);
}

// Round 2
// 355.869 us; speedup vs baseline: 1.2302x; 1.2302x over previous
//
#include <hip/hip_runtime.h>

// HebbFF T=128,B=8,N=512,D=256,O=1.
// Key insight: h_mult/A_mult never depend on h_add/A_add, so the recurrence
// factors into two sync-free sequential kernels:
//   k1: h_mult chain (per-wave private A_mult rows), writes h[T][B][N] to ws
//   k2: h_add chain (per-wave private A_add rows), reads h, writes per-wave
//       y partials part[T][B][64]
//   k3: reduce 64 partials + b_final + sigmoid -> out[T*B]
// No barriers, no atomics, no LDS anywhere. ws = 2.36 MB.

#define T_ 128
#define B_ 8
#define N_ 512
#define D_ 256
#define NTHREADS 512
#define NWAVES 8
#define RW1 8            // rows/wave k1: 8 waves*8 rows = 64 rows/block, 8 blocks/group
#define RW2 8            // rows/wave k2
#define GB 8             // blocks per group (batch); group = blockIdx & 7 -> XCD-affine
#define HOFF (T_ * B_ * N_)   // part[] offset in floats

__device__ __forceinline__ float wave_sum(float v) {
#pragma unroll
  for (int m = 1; m < 64; m <<= 1) v += __shfl_xor(v, m, 64);
  return v;
}
__device__ __forceinline__ float sigmoid_f(float z) {
  return __builtin_amdgcn_rcpf(1.f + __expf(-z));
}
__device__ __forceinline__ float tanh_f(float z) {
  return 1.f - 2.f * __builtin_amdgcn_rcpf(1.f + __expf(2.f * z));
}

// ---------------- kernel 1: h_mult / A_mult chain ----------------
__global__ void __launch_bounds__(NTHREADS)
hebb_part1(const float* __restrict__ x, const float* __restrict__ w_mult,
           const float* __restrict__ b_mult, const float* __restrict__ p_lm,
           const float* __restrict__ p_em, float* __restrict__ ws) {
  const int g = blockIdx.x & 7;
  const int blk = blockIdx.x >> 3;
  const int wave = threadIdx.x >> 6;
  const int lane = threadIdx.x & 63;
  const int n0 = (blk * NWAVES + wave) * RW1;

  const float lam = sigmoid_f(p_lm[0]);
  const float eta = p_em[0];

  float wm[RW1][4], Am[RW1][4], bm[RW1];
#pragma unroll
  for (int r = 0; r < RW1; ++r) {
    bm[r] = b_mult[n0 + r];
#pragma unroll
    for (int j = 0; j < 4; ++j) {
      wm[r][j] = w_mult[(n0 + r) * D_ + lane + 64 * j];
      Am[r][j] = 0.f;
    }
  }

  float xv0[4], xv1[4], xv2[4], xv3[4];
#define LOADX(buf, t)                                      \
  {                                                        \
    const float* xt = x + ((t) * B_ + g) * D_;             \
    _Pragma("unroll") for (int j = 0; j < 4; ++j)          \
        buf[j] = xt[lane + 64 * j];                        \
  }
#define STEP1(buf, t)                                               \
  {                                                                 \
    float hmv[RW1];                                                 \
    _Pragma("unroll") for (int r = 0; r < RW1; ++r) {               \
      float acc = 0.f;                                              \
      _Pragma("unroll") for (int j = 0; j < 4; ++j) {               \
        const float wx = wm[r][j] * buf[j];                         \
        acc = __builtin_fmaf(wx, Am[r][j], acc) + wx;               \
      }                                                             \
      acc = wave_sum(acc) + bm[r];                                  \
      const float hm = tanh_f(acc);                                 \
      hmv[r] = hm;                                                  \
      const float c = eta * hm;                                     \
      _Pragma("unroll") for (int j = 0; j < 4; ++j)                 \
          Am[r][j] = __builtin_fmaf(lam, Am[r][j], c * buf[j]);     \
    }                                                               \
    if (lane == 0) {                                                \
      float* hb = ws + ((t) * B_ + g) * N_ + n0;                    \
      float4 v0 = make_float4(hmv[0], hmv[1], hmv[2], hmv[3]);      \
      float4 v1 = make_float4(hmv[4], hmv[5], hmv[6], hmv[7]);      \
      *(float4*)hb = v0;                                            \
      *(float4*)(hb + 4) = v1;                                      \
    }                                                               \
  }

  LOADX(xv0, 0) LOADX(xv1, 1) LOADX(xv2, 2) LOADX(xv3, 3)
  for (int t = 0; t < T_; t += 4) {
    STEP1(xv0, t)
    if (t + 4 < T_) LOADX(xv0, t + 4)
    STEP1(xv1, t + 1)
    if (t + 5 < T_) LOADX(xv1, t + 5)
    STEP1(xv2, t + 2)
    if (t + 6 < T_) LOADX(xv2, t + 6)
    STEP1(xv3, t + 3)
    if (t + 7 < T_) LOADX(xv3, t + 7)
  }
#undef LOADX
#undef STEP1
}

// ---------------- kernel 2: h_add / A_add chain ----------------
__global__ void __launch_bounds__(NTHREADS)
hebb_part2(const float* __restrict__ w_add, const float* __restrict__ b_add,
           const float* __restrict__ w_final, const float* __restrict__ p_la,
           const float* __restrict__ p_ea, float* __restrict__ ws) {
  const int g = blockIdx.x & 7;
  const int blk = blockIdx.x >> 3;
  const int wave = threadIdx.x >> 6;
  const int lane = threadIdx.x & 63;
  const int n0 = (blk * NWAVES + wave) * RW2;

  const float lam = sigmoid_f(p_la[0]);
  const float eta = p_ea[0];

  float Sa[RW2][8], wb[RW2][8], ba[RW2], wf[RW2];
#pragma unroll
  for (int r = 0; r < RW2; ++r) {
    ba[r] = b_add[n0 + r];
    wf[r] = w_final[n0 + r];
#pragma unroll
    for (int k = 0; k < 8; ++k) {
      const float wa = w_add[(n0 + r) * N_ + lane + 64 * k];
      Sa[r][k] = wa;                  // S = A_add + w_add, A_add(0)=0
      wb[r][k] = (1.f - lam) * wa;    // (1-lam)*w_add update term
    }
  }

  const float* hsrc = ws;
  float* part = ws + HOFF;   // [t][g][blk*8+wave]

  float hv0[8], hv1[8], hv2[8], hv3[8];
#define LOADH(buf, t)                                      \
  {                                                        \
    const float* hb = hsrc + ((t) * B_ + g) * N_;          \
    _Pragma("unroll") for (int k = 0; k < 8; ++k)          \
        buf[k] = hb[lane + 64 * k];                        \
  }
#define STEP2(buf, t)                                                 \
  {                                                                   \
    float py = 0.f;                                                   \
    _Pragma("unroll") for (int r = 0; r < RW2; ++r) {                 \
      float a0 = 0.f, a1 = 0.f;                                       \
      _Pragma("unroll") for (int k = 0; k < 8; k += 2) {              \
        a0 = __builtin_fmaf(Sa[r][k], buf[k], a0);                    \
        a1 = __builtin_fmaf(Sa[r][k + 1], buf[k + 1], a1);            \
      }                                                               \
      float acc = wave_sum(a0 + a1) + ba[r];                          \
      const float ha = sigmoid_f(acc);                                \
      const float c = eta * ha;                                       \
      _Pragma("unroll") for (int k = 0; k < 8; ++k)                   \
          Sa[r][k] = __builtin_fmaf(                                  \
              lam, Sa[r][k], __builtin_fmaf(c, buf[k], wb[r][k]));    \
      py = __builtin_fmaf(wf[r], ha, py);                             \
    }                                                                 \
    if (lane == 0)                                                    \
      part[((t) * B_ + g) * 64 + blk * NWAVES + wave] = py;           \
  }

  LOADH(hv0, 0) LOADH(hv1, 1) LOADH(hv2, 2) LOADH(hv3, 3)
  for (int t = 0; t < T_; t += 4) {
    STEP2(hv0, t)
    if (t + 4 < T_) LOADH(hv0, t + 4)
    STEP2(hv1, t + 1)
    if (t + 5 < T_) LOADH(hv1, t + 5)
    STEP2(hv2, t + 2)
    if (t + 6 < T_) LOADH(hv2, t + 6)
    STEP2(hv3, t + 3)
    if (t + 7 < T_) LOADH(hv3, t + 7)
  }
#undef LOADH
#undef STEP2
}

// ---------------- kernel 3: reduce partials + final sigmoid ----------------
__global__ void hebb_final(const float* __restrict__ ws,
                           const float* __restrict__ b_final,
                           float* __restrict__ out) {
  const int tb = blockIdx.x * blockDim.x + threadIdx.x;  // t*8 + b
  if (tb >= T_ * B_) return;
  const float* p = ws + HOFF + tb * 64;
  float s = b_final[0];
#pragma unroll
  for (int i = 0; i < 16; ++i) {
    const float4 v = ((const float4*)p)[i];
    s += (v.x + v.y) + (v.z + v.w);
  }
  out[tb] = sigmoid_f(s);
}

extern "C" void kernel_launch(void* const* d_in, const int* in_sizes, int n_in,
                              void* d_out, int out_size, void* d_ws,
                              size_t ws_size, hipStream_t stream) {
  const float* x       = (const float*)d_in[0];
  const float* w_mult  = (const float*)d_in[1];
  const float* b_mult  = (const float*)d_in[2];
  const float* w_add   = (const float*)d_in[3];
  const float* b_add   = (const float*)d_in[4];
  const float* w_final = (const float*)d_in[5];
  const float* b_final = (const float*)d_in[6];
  const float* p_lm    = (const float*)d_in[7];
  const float* p_la    = (const float*)d_in[8];
  const float* p_em    = (const float*)d_in[9];
  const float* p_ea    = (const float*)d_in[10];
  float* out = (float*)d_out;
  float* ws  = (float*)d_ws;

  hipLaunchKernelGGL(hebb_part1, dim3(GB * B_), dim3(NTHREADS), 0, stream,
                     x, w_mult, b_mult, p_lm, p_em, ws);
  hipLaunchKernelGGL(hebb_part2, dim3(GB * B_), dim3(NTHREADS), 0, stream,
                     w_add, b_add, w_final, p_la, p_ea, ws);
  hipLaunchKernelGGL(hebb_final, dim3(2), dim3(512), 0, stream,
                     ws, b_final, out);
}

// Round 3
// 118.392 us; speedup vs baseline: 3.6979x; 3.0059x over previous
//
#include <hip/hip_runtime.h>

// HebbFF T=128,B=8,N=512,D=256,O=1. Two sync-free sequential kernels
// (h_mult chain never depends on h_add chain) + tiny reduce.
// R3: 256 blocks (all CUs), 2 rows/wave (no spills), DPP wave reduction
// (6 v_add_f32-dpp instead of 6 ds_bpermute), packed-f32 FMAs (v_pk_fma_f32).
// ws: h[T][B][N] (2MB) + part[T*B][256] (1MB).

#define T_ 128
#define B_ 8
#define N_ 512
#define D_ 256
#define NTHREADS 512
#define HOFF (T_ * B_ * N_)

typedef float v2f __attribute__((ext_vector_type(2)));

__device__ __forceinline__ v2f v2(float s) { v2f r; r.x = s; r.y = s; return r; }

// Canonical GCN wave64 sum: row_shr 1/2/4/8 + row_bcast15/31; total in lane 63.
__device__ __forceinline__ float dpp_wave_sum(float v) {
#define UPD(ctrl)                                                              \
  v += __int_as_float(                                                         \
      __builtin_amdgcn_update_dpp(0, __float_as_int(v), ctrl, 0xf, 0xf, true))
  UPD(0x111); UPD(0x112); UPD(0x114); UPD(0x118); UPD(0x142); UPD(0x143);
#undef UPD
  return __int_as_float(__builtin_amdgcn_readlane(__float_as_int(v), 63));
}
__device__ __forceinline__ float sigmoid_f(float z) {
  return __builtin_amdgcn_rcpf(1.f + __expf(-z));
}
__device__ __forceinline__ float tanh_f(float z) {
  return 1.f - 2.f * __builtin_amdgcn_rcpf(1.f + __expf(2.f * z));
}

// ---------------- kernel 1: h_mult / A_mult chain ----------------
// 256 blocks: g=blk&7 (XCD-affine), sub=blk>>3 in [0,32); 8 waves x 2 rows.
// State per lane: Bm = A_mult+1 (so dot = sum wm*Bm*x), 2 rows x 2 v2f.
__global__ void __launch_bounds__(NTHREADS)
hebb_part1(const float* __restrict__ x, const float* __restrict__ w_mult,
           const float* __restrict__ b_mult, const float* __restrict__ p_lm,
           const float* __restrict__ p_em, float* __restrict__ ws) {
  const int g = blockIdx.x & 7, sub = blockIdx.x >> 3;
  const int wave = threadIdx.x >> 6, lane = threadIdx.x & 63;
  const int n0 = (sub * 8 + wave) * 2;

  const float lam = sigmoid_f(p_lm[0]);
  const float eta = p_em[0];
  const v2f lam2 = v2(lam), klam2 = v2(1.f - lam);

  v2f wm[2][2], Bm[2][2];
  float bm[2];
#pragma unroll
  for (int r = 0; r < 2; ++r) {
    bm[r] = b_mult[n0 + r];
#pragma unroll
    for (int c = 0; c < 2; ++c) {
      wm[r][c] = *(const v2f*)&w_mult[(n0 + r) * D_ + c * 128 + 2 * lane];
      Bm[r][c] = v2(1.f);
    }
  }

  v2f xv[4][2];
#define LOADX(i, t)                                                            \
  {                                                                            \
    const float* xt = x + ((t) * B_ + g) * D_ + 2 * lane;                      \
    xv[i][0] = *(const v2f*)&xt[0];                                            \
    xv[i][1] = *(const v2f*)&xt[128];                                          \
  }
#define STEP1(i, t)                                                            \
  {                                                                            \
    float hmv[2];                                                              \
    _Pragma("unroll") for (int r = 0; r < 2; ++r) {                            \
      v2f a = wm[r][0] * xv[i][0] * Bm[r][0];                                  \
      a = __builtin_elementwise_fma(wm[r][1] * xv[i][1], Bm[r][1], a);         \
      const float z = dpp_wave_sum(a.x + a.y) + bm[r];                         \
      const float hm = tanh_f(z);                                              \
      hmv[r] = hm;                                                             \
      const v2f c2 = v2(eta * hm);                                             \
      _Pragma("unroll") for (int c = 0; c < 2; ++c) {                          \
        v2f inner = __builtin_elementwise_fma(c2, xv[i][c], klam2);            \
        Bm[r][c] = __builtin_elementwise_fma(lam2, Bm[r][c], inner);           \
      }                                                                        \
    }                                                                          \
    if (lane == 0) {                                                           \
      v2f hv2; hv2.x = hmv[0]; hv2.y = hmv[1];                                 \
      *(v2f*)(ws + ((t) * B_ + g) * N_ + n0) = hv2;                            \
    }                                                                          \
  }

  LOADX(0, 0) LOADX(1, 1) LOADX(2, 2) LOADX(3, 3)
  for (int t = 0; t < T_; t += 4) {
    STEP1(0, t)
    if (t + 4 < T_) LOADX(0, t + 4)
    STEP1(1, t + 1)
    if (t + 5 < T_) LOADX(1, t + 5)
    STEP1(2, t + 2)
    if (t + 6 < T_) LOADX(2, t + 6)
    STEP1(3, t + 3)
    if (t + 7 < T_) LOADX(3, t + 7)
  }
#undef LOADX
#undef STEP1
}

// ---------------- kernel 2: h_add / A_add chain ----------------
// Same grid. State per lane: Sa = A_add + w_add (dot = Sa . h),
// wb = (1-lam)*w_add. 2 rows x 4 v2f each.
__global__ void __launch_bounds__(NTHREADS)
hebb_part2(const float* __restrict__ w_add, const float* __restrict__ b_add,
           const float* __restrict__ w_final, const float* __restrict__ p_la,
           const float* __restrict__ p_ea, float* __restrict__ ws) {
  const int g = blockIdx.x & 7, sub = blockIdx.x >> 3;
  const int wave = threadIdx.x >> 6, lane = threadIdx.x & 63;
  const int n0 = (sub * 8 + wave) * 2;

  const float lam = sigmoid_f(p_la[0]);
  const float eta = p_ea[0];
  const v2f lam2 = v2(lam);
  const float klam = 1.f - lam;

  v2f Sa[2][4], wb[2][4];
  float ba[2], wf[2];
#pragma unroll
  for (int r = 0; r < 2; ++r) {
    ba[r] = b_add[n0 + r];
    wf[r] = w_final[n0 + r];
#pragma unroll
    for (int c = 0; c < 4; ++c) {
      const v2f wa = *(const v2f*)&w_add[(n0 + r) * N_ + c * 128 + 2 * lane];
      Sa[r][c] = wa;
      wb[r][c] = wa * klam;
    }
  }

  const float* hsrc = ws;
  float* part = ws + HOFF;

  v2f hv[4][4];
#define LOADH(i, t)                                                            \
  {                                                                            \
    const float* hb = hsrc + ((t) * B_ + g) * N_ + 2 * lane;                   \
    hv[i][0] = *(const v2f*)&hb[0];                                            \
    hv[i][1] = *(const v2f*)&hb[128];                                          \
    hv[i][2] = *(const v2f*)&hb[256];                                          \
    hv[i][3] = *(const v2f*)&hb[384];                                          \
  }
#define STEP2(i, t)                                                            \
  {                                                                            \
    float py = 0.f;                                                            \
    _Pragma("unroll") for (int r = 0; r < 2; ++r) {                            \
      v2f a0 = Sa[r][0] * hv[i][0];                                            \
      v2f a1 = Sa[r][1] * hv[i][1];                                            \
      a0 = __builtin_elementwise_fma(Sa[r][2], hv[i][2], a0);                  \
      a1 = __builtin_elementwise_fma(Sa[r][3], hv[i][3], a1);                  \
      const v2f a = a0 + a1;                                                   \
      const float z = dpp_wave_sum(a.x + a.y) + ba[r];                         \
      const float ha = sigmoid_f(z);                                           \
      const v2f c2 = v2(eta * ha);                                             \
      _Pragma("unroll") for (int c = 0; c < 4; ++c) {                          \
        v2f inner = __builtin_elementwise_fma(c2, hv[i][c], wb[r][c]);         \
        Sa[r][c] = __builtin_elementwise_fma(lam2, Sa[r][c], inner);           \
      }                                                                        \
      py = __builtin_fmaf(wf[r], ha, py);                                      \
    }                                                                          \
    if (lane == 0) part[((t) * B_ + g) * 256 + sub * 8 + wave] = py;           \
  }

  LOADH(0, 0) LOADH(1, 1) LOADH(2, 2) LOADH(3, 3)
  for (int t = 0; t < T_; t += 4) {
    STEP2(0, t)
    if (t + 4 < T_) LOADH(0, t + 4)
    STEP2(1, t + 1)
    if (t + 5 < T_) LOADH(1, t + 5)
    STEP2(2, t + 2)
    if (t + 6 < T_) LOADH(2, t + 6)
    STEP2(3, t + 3)
    if (t + 7 < T_) LOADH(3, t + 7)
  }
#undef LOADH
#undef STEP2
}

// ---------------- kernel 3: reduce 256 partials + final sigmoid ----------------
// One wave per (t,b): 64 lanes x float4, DPP reduce, lane0 writes.
__global__ void __launch_bounds__(NTHREADS)
hebb_final(const float* __restrict__ ws, const float* __restrict__ b_final,
           float* __restrict__ out) {
  const int wave = threadIdx.x >> 6, lane = threadIdx.x & 63;
  const int tb = blockIdx.x * 8 + wave;  // t*8+b, 1024 total
  const float4 v = *(const float4*)(ws + HOFF + tb * 256 + lane * 4);
  const float s = dpp_wave_sum((v.x + v.y) + (v.z + v.w));
  if (lane == 0) out[tb] = sigmoid_f(s + b_final[0]);
}

extern "C" void kernel_launch(void* const* d_in, const int* in_sizes, int n_in,
                              void* d_out, int out_size, void* d_ws,
                              size_t ws_size, hipStream_t stream) {
  const float* x       = (const float*)d_in[0];
  const float* w_mult  = (const float*)d_in[1];
  const float* b_mult  = (const float*)d_in[2];
  const float* w_add   = (const float*)d_in[3];
  const float* b_add   = (const float*)d_in[4];
  const float* w_final = (const float*)d_in[5];
  const float* b_final = (const float*)d_in[6];
  const float* p_lm    = (const float*)d_in[7];
  const float* p_la    = (const float*)d_in[8];
  const float* p_em    = (const float*)d_in[9];
  const float* p_ea    = (const float*)d_in[10];
  float* out = (float*)d_out;
  float* ws  = (float*)d_ws;

  hipLaunchKernelGGL(hebb_part1, dim3(256), dim3(NTHREADS), 0, stream,
                     x, w_mult, b_mult, p_lm, p_em, ws);
  hipLaunchKernelGGL(hebb_part2, dim3(256), dim3(NTHREADS), 0, stream,
                     w_add, b_add, w_final, p_la, p_ea, ws);
  hipLaunchKernelGGL(hebb_final, dim3(128), dim3(NTHREADS), 0, stream,
                     ws, b_final, out);
}

// Round 4
// 90.061 us; speedup vs baseline: 4.8612x; 1.3146x over previous
//
#include <hip/hip_runtime.h>

// HebbFF T=128,B=8,N=512,D=256,O=1. Two sync-free sequential chain kernels
// (h_mult chain feeds h_add chain, no feedback) + tiny reduce.
// R4: inputs staged via LDS in double-buffered 16-step chunks so the
// per-step critical path has NO global loads (only ds_read_b64, prefetched
// 1 step ahead). Output stores are fire-and-forget.
// ws: h[T][B][N] (2MB) + part[T*B][256] (1MB).

#define T_ 128
#define B_ 8
#define N_ 512
#define D_ 256
#define NTHREADS 512
#define CH 16                  // timesteps per staged chunk
#define NC (T_ / CH)           // 8 chunks
#define HOFF (T_ * B_ * N_)

typedef float v2f __attribute__((ext_vector_type(2)));

__device__ __forceinline__ v2f v2(float s) { v2f r; r.x = s; r.y = s; return r; }

// Canonical GCN wave64 sum: row_shr 1/2/4/8 + row_bcast15/31; total in lane 63.
__device__ __forceinline__ float dpp_wave_sum(float v) {
#define UPD(ctrl)                                                              \
  v += __int_as_float(                                                         \
      __builtin_amdgcn_update_dpp(0, __float_as_int(v), ctrl, 0xf, 0xf, true))
  UPD(0x111); UPD(0x112); UPD(0x114); UPD(0x118); UPD(0x142); UPD(0x143);
#undef UPD
  return __int_as_float(__builtin_amdgcn_readlane(__float_as_int(v), 63));
}
__device__ __forceinline__ float sigmoid_f(float z) {
  return __builtin_amdgcn_rcpf(1.f + __expf(-z));
}
__device__ __forceinline__ float tanh_f(float z) {
  return 1.f - 2.f * __builtin_amdgcn_rcpf(1.f + __expf(2.f * z));
}

// ---------------- kernel 1: h_mult / A_mult chain ----------------
// 256 blocks: g=blk&7 (XCD-affine), sub=blk>>3; 8 waves x 2 rows/wave.
// Bm = A_mult + 1 so dot = sum wm*Bm*x.
__global__ void __launch_bounds__(NTHREADS)
hebb_part1(const float* __restrict__ x, const float* __restrict__ w_mult,
           const float* __restrict__ b_mult, const float* __restrict__ p_lm,
           const float* __restrict__ p_em, float* __restrict__ ws) {
  const int g = blockIdx.x & 7, sub = blockIdx.x >> 3;
  const int wave = threadIdx.x >> 6, lane = threadIdx.x & 63;
  const int n0 = (sub * 8 + wave) * 2;

  __shared__ float xs[2][CH][D_];  // 32 KB double-buffered x chunks

  const float lam = sigmoid_f(p_lm[0]);
  const float eta = p_em[0];
  const v2f lam2 = v2(lam), klam2 = v2(1.f - lam);

  v2f wm[2][2], Bm[2][2];
  float bm[2];
#pragma unroll
  for (int r = 0; r < 2; ++r) {
    bm[r] = b_mult[n0 + r];
#pragma unroll
    for (int c = 0; c < 2; ++c) {
      wm[r][c] = *(const v2f*)&w_mult[(n0 + r) * D_ + c * 128 + 2 * lane];
      Bm[r][c] = v2(1.f);
    }
  }

  float4 st[2];  // staged x rows for next chunk (wave handles rows k*8+wave)
  auto issue_stage = [&](int c) {
#pragma unroll
    for (int k = 0; k < 2; ++k) {
      const int trow = c * CH + k * 8 + wave;
      st[k] = *(const float4*)&x[(trow * B_ + g) * D_ + 4 * lane];
    }
  };
  auto write_stage = [&](int c) {
#pragma unroll
    for (int k = 0; k < 2; ++k)
      *(float4*)&xs[c & 1][k * 8 + wave][4 * lane] = st[k];
  };

  issue_stage(0);
  write_stage(0);
  __syncthreads();

  v2f xv[2][2];  // ping-pong per-step input
  auto ldx = [&](int buf, int cb, int tl) {
    xv[buf][0] = *(const v2f*)&xs[cb][tl][2 * lane];
    xv[buf][1] = *(const v2f*)&xs[cb][tl][128 + 2 * lane];
  };

  for (int c = 0; c < NC; ++c) {
    if (c + 1 < NC) issue_stage(c + 1);
    const int cb = c & 1;
    ldx(0, cb, 0);
#pragma unroll
    for (int tl = 0; tl < CH; ++tl) {
      const int buf = tl & 1;
      if (tl + 1 < CH) ldx(buf ^ 1, cb, tl + 1);
      float hmv[2];
#pragma unroll
      for (int r = 0; r < 2; ++r) {
        v2f a = wm[r][0] * xv[buf][0] * Bm[r][0];
        a = __builtin_elementwise_fma(wm[r][1] * xv[buf][1], Bm[r][1], a);
        const float z = dpp_wave_sum(a.x + a.y) + bm[r];
        const float hm = tanh_f(z);
        hmv[r] = hm;
        const v2f c2 = v2(eta * hm);
#pragma unroll
        for (int cc = 0; cc < 2; ++cc) {
          v2f inner = __builtin_elementwise_fma(c2, xv[buf][cc], klam2);
          Bm[r][cc] = __builtin_elementwise_fma(lam2, Bm[r][cc], inner);
        }
      }
      if (lane == 0) {
        v2f hv2; hv2.x = hmv[0]; hv2.y = hmv[1];
        *(v2f*)(ws + ((c * CH + tl) * B_ + g) * N_ + n0) = hv2;
      }
    }
    if (c + 1 < NC) write_stage(c + 1);
    __syncthreads();
  }
}

// ---------------- kernel 2: h_add / A_add chain ----------------
// Sa = A_add + w_add; wb = (1-lam)*w_add.
__global__ void __launch_bounds__(NTHREADS)
hebb_part2(const float* __restrict__ w_add, const float* __restrict__ b_add,
           const float* __restrict__ w_final, const float* __restrict__ p_la,
           const float* __restrict__ p_ea, float* __restrict__ ws) {
  const int g = blockIdx.x & 7, sub = blockIdx.x >> 3;
  const int wave = threadIdx.x >> 6, lane = threadIdx.x & 63;
  const int n0 = (sub * 8 + wave) * 2;

  __shared__ float hs[2][CH][N_];  // 64 KB double-buffered h chunks

  const float lam = sigmoid_f(p_la[0]);
  const float eta = p_ea[0];
  const v2f lam2 = v2(lam);
  const float klam = 1.f - lam;

  v2f Sa[2][4], wb[2][4];
  float ba[2], wf[2];
#pragma unroll
  for (int r = 0; r < 2; ++r) {
    ba[r] = b_add[n0 + r];
    wf[r] = w_final[n0 + r];
#pragma unroll
    for (int c = 0; c < 4; ++c) {
      const v2f wa = *(const v2f*)&w_add[(n0 + r) * N_ + c * 128 + 2 * lane];
      Sa[r][c] = wa;
      wb[r][c] = wa * klam;
    }
  }

  const float* hsrc = ws;
  float* part = ws + HOFF;

  float4 st[2][2];  // staged h rows: [k][half]
  auto issue_stage = [&](int c) {
#pragma unroll
    for (int k = 0; k < 2; ++k) {
      const int trow = c * CH + k * 8 + wave;
#pragma unroll
      for (int j = 0; j < 2; ++j)
        st[k][j] =
            *(const float4*)&hsrc[(trow * B_ + g) * N_ + j * 256 + 4 * lane];
    }
  };
  auto write_stage = [&](int c) {
#pragma unroll
    for (int k = 0; k < 2; ++k)
#pragma unroll
      for (int j = 0; j < 2; ++j)
        *(float4*)&hs[c & 1][k * 8 + wave][j * 256 + 4 * lane] = st[k][j];
  };

  issue_stage(0);
  write_stage(0);
  __syncthreads();

  v2f hv[2][4];
  auto ldh = [&](int buf, int cb, int tl) {
#pragma unroll
    for (int cc = 0; cc < 4; ++cc)
      hv[buf][cc] = *(const v2f*)&hs[cb][tl][cc * 128 + 2 * lane];
  };

  for (int c = 0; c < NC; ++c) {
    if (c + 1 < NC) issue_stage(c + 1);
    const int cb = c & 1;
    ldh(0, cb, 0);
#pragma unroll
    for (int tl = 0; tl < CH; ++tl) {
      const int buf = tl & 1;
      if (tl + 1 < CH) ldh(buf ^ 1, cb, tl + 1);
      float py = 0.f;
#pragma unroll
      for (int r = 0; r < 2; ++r) {
        v2f a0 = Sa[r][0] * hv[buf][0];
        v2f a1 = Sa[r][1] * hv[buf][1];
        a0 = __builtin_elementwise_fma(Sa[r][2], hv[buf][2], a0);
        a1 = __builtin_elementwise_fma(Sa[r][3], hv[buf][3], a1);
        const v2f a = a0 + a1;
        const float z = dpp_wave_sum(a.x + a.y) + ba[r];
        const float ha = sigmoid_f(z);
        const v2f c2 = v2(eta * ha);
#pragma unroll
        for (int cc = 0; cc < 4; ++cc) {
          v2f inner = __builtin_elementwise_fma(c2, hv[buf][cc], wb[r][cc]);
          Sa[r][cc] = __builtin_elementwise_fma(lam2, Sa[r][cc], inner);
        }
        py = __builtin_fmaf(wf[r], ha, py);
      }
      if (lane == 0)
        part[((c * CH + tl) * B_ + g) * 256 + sub * 8 + wave] = py;
    }
    if (c + 1 < NC) write_stage(c + 1);
    __syncthreads();
  }
}

// ---------------- kernel 3: reduce 256 partials + final sigmoid ----------------
__global__ void __launch_bounds__(NTHREADS)
hebb_final(const float* __restrict__ ws, const float* __restrict__ b_final,
           float* __restrict__ out) {
  const int wave = threadIdx.x >> 6, lane = threadIdx.x & 63;
  const int tb = blockIdx.x * 8 + wave;  // t*8+b, 1024 total
  const float4 v = *(const float4*)(ws + HOFF + tb * 256 + lane * 4);
  const float s = dpp_wave_sum((v.x + v.y) + (v.z + v.w));
  if (lane == 0) out[tb] = sigmoid_f(s + b_final[0]);
}

extern "C" void kernel_launch(void* const* d_in, const int* in_sizes, int n_in,
                              void* d_out, int out_size, void* d_ws,
                              size_t ws_size, hipStream_t stream) {
  const float* x       = (const float*)d_in[0];
  const float* w_mult  = (const float*)d_in[1];
  const float* b_mult  = (const float*)d_in[2];
  const float* w_add   = (const float*)d_in[3];
  const float* b_add   = (const float*)d_in[4];
  const float* w_final = (const float*)d_in[5];
  const float* b_final = (const float*)d_in[6];
  const float* p_lm    = (const float*)d_in[7];
  const float* p_la    = (const float*)d_in[8];
  const float* p_em    = (const float*)d_in[9];
  const float* p_ea    = (const float*)d_in[10];
  float* out = (float*)d_out;
  float* ws  = (float*)d_ws;

  hipLaunchKernelGGL(hebb_part1, dim3(256), dim3(NTHREADS), 0, stream,
                     x, w_mult, b_mult, p_lm, p_em, ws);
  hipLaunchKernelGGL(hebb_part2, dim3(256), dim3(NTHREADS), 0, stream,
                     w_add, b_add, w_final, p_la, p_ea, ws);
  hipLaunchKernelGGL(hebb_final, dim3(128), dim3(NTHREADS), 0, stream,
                     ws, b_final, out);
}

// Round 5
// 76.652 us; speedup vs baseline: 5.7116x; 1.1749x over previous
//
#include <hip/hip_runtime.h>
#include <cstdint>

// HebbFF T=128,B=8,N=512,D=256,O=1. Two sync-free sequential chain kernels
// (h_mult chain feeds h_add chain, no feedback) + tiny reduce.
// R5: kill part2's register spills (R4: VGPR=52, 8MB scratch writes on the
// recurrence chain): __launch_bounds__(512,2) gives the allocator headroom,
// and chunk staging now uses global_load_lds (HBM->LDS direct, no staging
// registers, no write pass). ws: h[T][B][N] (2MB) + part[T*B][256] (1MB).

#define T_ 128
#define B_ 8
#define N_ 512
#define D_ 256
#define NTHREADS 512
#define CH 16                  // timesteps per staged chunk
#define NC (T_ / CH)           // 8 chunks
#define HOFF (T_ * B_ * N_)

typedef float v2f __attribute__((ext_vector_type(2)));

__device__ __forceinline__ v2f v2(float s) { v2f r; r.x = s; r.y = s; return r; }

// async 16B/lane global->LDS: lds dest = uniform base + lane*16 (linear),
// global src per-lane. Tracked by vmcnt; __syncthreads drains it.
__device__ __forceinline__ void load_lds16(const float* g, float* l) {
  __builtin_amdgcn_global_load_lds(
      (const __attribute__((address_space(1))) uint32_t*)(const void*)g,
      (__attribute__((address_space(3))) uint32_t*)(void*)l, 16, 0, 0);
}

// Canonical GCN wave64 sum: row_shr 1/2/4/8 + row_bcast15/31; total in lane 63.
__device__ __forceinline__ float dpp_wave_sum(float v) {
#define UPD(ctrl)                                                              \
  v += __int_as_float(                                                         \
      __builtin_amdgcn_update_dpp(0, __float_as_int(v), ctrl, 0xf, 0xf, true))
  UPD(0x111); UPD(0x112); UPD(0x114); UPD(0x118); UPD(0x142); UPD(0x143);
#undef UPD
  return __int_as_float(__builtin_amdgcn_readlane(__float_as_int(v), 63));
}
__device__ __forceinline__ float sigmoid_f(float z) {
  return __builtin_amdgcn_rcpf(1.f + __expf(-z));
}
__device__ __forceinline__ float tanh_f(float z) {
  return 1.f - 2.f * __builtin_amdgcn_rcpf(1.f + __expf(2.f * z));
}

// ---------------- kernel 1: h_mult / A_mult chain ----------------
// 256 blocks: g=blk&7 (XCD-affine), sub=blk>>3; 8 waves x 2 rows/wave.
// Bm = A_mult + 1 so dot = sum wm*Bm*x.
__global__ void __launch_bounds__(NTHREADS, 2)
hebb_part1(const float* __restrict__ x, const float* __restrict__ w_mult,
           const float* __restrict__ b_mult, const float* __restrict__ p_lm,
           const float* __restrict__ p_em, float* __restrict__ ws) {
  const int g = blockIdx.x & 7, sub = blockIdx.x >> 3;
  const int wave = threadIdx.x >> 6, lane = threadIdx.x & 63;
  const int n0 = (sub * 8 + wave) * 2;

  __shared__ float xs[2][CH][D_];  // 32 KB double-buffered x chunks

  const float lam = sigmoid_f(p_lm[0]);
  const float eta = p_em[0];
  const v2f lam2 = v2(lam), klam2 = v2(1.f - lam);

  v2f wm[2][2], Bm[2][2];
  float bm[2];
#pragma unroll
  for (int r = 0; r < 2; ++r) {
    bm[r] = b_mult[n0 + r];
#pragma unroll
    for (int c = 0; c < 2; ++c) {
      wm[r][c] = *(const v2f*)&w_mult[(n0 + r) * D_ + c * 128 + 2 * lane];
      Bm[r][c] = v2(1.f);
    }
  }

  // stage chunk c into xs[c&1]: 16 rows x 1024B; each wave 2 rows, 1 op each
  auto issue_stage = [&](int c) {
#pragma unroll
    for (int k = 0; k < 2; ++k) {
      const int row = k * 8 + wave;
      const int trow = c * CH + row;
      load_lds16(&x[(trow * B_ + g) * D_ + 4 * lane], &xs[c & 1][row][0]);
    }
  };

  issue_stage(0);
  __syncthreads();  // vmcnt(0) drain + barrier: chunk 0 ready

  v2f xv[2][2];  // ping-pong per-step input
  auto ldx = [&](int buf, int cb, int tl) {
    xv[buf][0] = *(const v2f*)&xs[cb][tl][2 * lane];
    xv[buf][1] = *(const v2f*)&xs[cb][tl][128 + 2 * lane];
  };

  for (int c = 0; c < NC; ++c) {
    if (c + 1 < NC) issue_stage(c + 1);
    const int cb = c & 1;
    ldx(0, cb, 0);
#pragma unroll
    for (int tl = 0; tl < CH; ++tl) {
      const int buf = tl & 1;
      if (tl + 1 < CH) ldx(buf ^ 1, cb, tl + 1);
      float hmv[2];
#pragma unroll
      for (int r = 0; r < 2; ++r) {
        v2f a = wm[r][0] * xv[buf][0] * Bm[r][0];
        a = __builtin_elementwise_fma(wm[r][1] * xv[buf][1], Bm[r][1], a);
        const float z = dpp_wave_sum(a.x + a.y) + bm[r];
        const float hm = tanh_f(z);
        hmv[r] = hm;
        const v2f c2 = v2(eta * hm);
#pragma unroll
        for (int cc = 0; cc < 2; ++cc) {
          v2f inner = __builtin_elementwise_fma(c2, xv[buf][cc], klam2);
          Bm[r][cc] = __builtin_elementwise_fma(lam2, Bm[r][cc], inner);
        }
      }
      if (lane == 0) {
        v2f hv2; hv2.x = hmv[0]; hv2.y = hmv[1];
        *(v2f*)(ws + ((c * CH + tl) * B_ + g) * N_ + n0) = hv2;
      }
    }
    __syncthreads();  // drains next-chunk stage loads; protects buffer reuse
  }
}

// ---------------- kernel 2: h_add / A_add chain ----------------
// Sa = A_add + w_add; wb = (1-lam)*w_add.
__global__ void __launch_bounds__(NTHREADS, 2)
hebb_part2(const float* __restrict__ w_add, const float* __restrict__ b_add,
           const float* __restrict__ w_final, const float* __restrict__ p_la,
           const float* __restrict__ p_ea, float* __restrict__ ws) {
  const int g = blockIdx.x & 7, sub = blockIdx.x >> 3;
  const int wave = threadIdx.x >> 6, lane = threadIdx.x & 63;
  const int n0 = (sub * 8 + wave) * 2;

  __shared__ float hs[2][CH][N_];  // 64 KB double-buffered h chunks

  const float lam = sigmoid_f(p_la[0]);
  const float eta = p_ea[0];
  const v2f lam2 = v2(lam);
  const float klam = 1.f - lam;

  v2f Sa[2][4], wb[2][4];
  float ba[2], wf[2];
#pragma unroll
  for (int r = 0; r < 2; ++r) {
    ba[r] = b_add[n0 + r];
    wf[r] = w_final[n0 + r];
#pragma unroll
    for (int c = 0; c < 4; ++c) {
      const v2f wa = *(const v2f*)&w_add[(n0 + r) * N_ + c * 128 + 2 * lane];
      Sa[r][c] = wa;
      wb[r][c] = wa * klam;
    }
  }

  const float* hsrc = ws;
  float* part = ws + HOFF;

  // stage chunk c: 16 rows x 2048B; each wave 2 rows x 2 halves
  auto issue_stage = [&](int c) {
#pragma unroll
    for (int k = 0; k < 2; ++k) {
      const int row = k * 8 + wave;
      const int trow = c * CH + row;
#pragma unroll
      for (int j = 0; j < 2; ++j)
        load_lds16(&hsrc[(trow * B_ + g) * N_ + j * 256 + 4 * lane],
                   &hs[c & 1][row][j * 256]);
    }
  };

  issue_stage(0);
  __syncthreads();

  v2f hv[2][4];
  auto ldh = [&](int buf, int cb, int tl) {
#pragma unroll
    for (int cc = 0; cc < 4; ++cc)
      hv[buf][cc] = *(const v2f*)&hs[cb][tl][cc * 128 + 2 * lane];
  };

  for (int c = 0; c < NC; ++c) {
    if (c + 1 < NC) issue_stage(c + 1);
    const int cb = c & 1;
    ldh(0, cb, 0);
#pragma unroll
    for (int tl = 0; tl < CH; ++tl) {
      const int buf = tl & 1;
      if (tl + 1 < CH) ldh(buf ^ 1, cb, tl + 1);
      float py = 0.f;
#pragma unroll
      for (int r = 0; r < 2; ++r) {
        v2f a0 = Sa[r][0] * hv[buf][0];
        v2f a1 = Sa[r][1] * hv[buf][1];
        a0 = __builtin_elementwise_fma(Sa[r][2], hv[buf][2], a0);
        a1 = __builtin_elementwise_fma(Sa[r][3], hv[buf][3], a1);
        const v2f a = a0 + a1;
        const float z = dpp_wave_sum(a.x + a.y) + ba[r];
        const float ha = sigmoid_f(z);
        const v2f c2 = v2(eta * ha);
#pragma unroll
        for (int cc = 0; cc < 4; ++cc) {
          v2f inner = __builtin_elementwise_fma(c2, hv[buf][cc], wb[r][cc]);
          Sa[r][cc] = __builtin_elementwise_fma(lam2, Sa[r][cc], inner);
        }
        py = __builtin_fmaf(wf[r], ha, py);
      }
      if (lane == 0)
        part[((c * CH + tl) * B_ + g) * 256 + sub * 8 + wave] = py;
    }
    __syncthreads();
  }
}

// ---------------- kernel 3: reduce 256 partials + final sigmoid ----------------
__global__ void __launch_bounds__(NTHREADS)
hebb_final(const float* __restrict__ ws, const float* __restrict__ b_final,
           float* __restrict__ out) {
  const int wave = threadIdx.x >> 6, lane = threadIdx.x & 63;
  const int tb = blockIdx.x * 8 + wave;  // t*8+b, 1024 total
  const float4 v = *(const float4*)(ws + HOFF + tb * 256 + lane * 4);
  const float s = dpp_wave_sum((v.x + v.y) + (v.z + v.w));
  if (lane == 0) out[tb] = sigmoid_f(s + b_final[0]);
}

extern "C" void kernel_launch(void* const* d_in, const int* in_sizes, int n_in,
                              void* d_out, int out_size, void* d_ws,
                              size_t ws_size, hipStream_t stream) {
  const float* x       = (const float*)d_in[0];
  const float* w_mult  = (const float*)d_in[1];
  const float* b_mult  = (const float*)d_in[2];
  const float* w_add   = (const float*)d_in[3];
  const float* b_add   = (const float*)d_in[4];
  const float* w_final = (const float*)d_in[5];
  const float* b_final = (const float*)d_in[6];
  const float* p_lm    = (const float*)d_in[7];
  const float* p_la    = (const float*)d_in[8];
  const float* p_em    = (const float*)d_in[9];
  const float* p_ea    = (const float*)d_in[10];
  float* out = (float*)d_out;
  float* ws  = (float*)d_ws;

  hipLaunchKernelGGL(hebb_part1, dim3(256), dim3(NTHREADS), 0, stream,
                     x, w_mult, b_mult, p_lm, p_em, ws);
  hipLaunchKernelGGL(hebb_part2, dim3(256), dim3(NTHREADS), 0, stream,
                     w_add, b_add, w_final, p_la, p_ea, ws);
  hipLaunchKernelGGL(hebb_final, dim3(128), dim3(NTHREADS), 0, stream,
                     ws, b_final, out);
}